// Round 20
// baseline (132.744 us; speedup 1.0000x reference)
//
#include <hip/hip_runtime.h>

// UpsampleRFFT (zero-insert 2x + ideal half-band low-pass, circular), closed form:
//   g[j] = sign*cot(pi*(2j+1)/256)/128, sign=+ if j even
//   out[2r][2i]   = x[r][i] (exact fp32)      out[2r][2i+1] = T[r][i],  T = X*G
//   out[2p+1][c]  = sum_m g[(p-m)&127] * E[m][c],  E = even rows
// R20: 2 IMAGES per block (same c-quarter -> invariant addressing), Et double-
// buffered (2x16KB). After tile0's x regs are consumed (cvt->xa), the SAME
// xlo/xhi registers are re-issued with tile1's loads -> HBM latency hides
// under tile0 phase A + barrier + phase B (T14 issue-early). Requires the R16
// lgkmcnt-only barrier: __syncthreads would drain vmcnt(0) and kill prefetch.
//
// Kept lessons: rule #20 (static reg indices, runtime offsets in ADDRESSES);
// R10 no nt stores; R13 Et XOR swizzle + phase-B 2-p-tile frag reuse;
// R18 constexpr tap table (no init kernel); R19 quarter split (16KB Et).

typedef __bf16 bf16x8 __attribute__((ext_vector_type(8)));
typedef float  f32x4  __attribute__((ext_vector_type(4)));

#define PI_D 3.14159265358979323846

// ---- constexpr trig (Taylor, |x| <= pi, double: ~1e-11 rel) ----
constexpr double csin(double x) {
    double t = x, s = x; const double x2 = x * x;
    for (int k = 1; k < 13; ++k) { t *= -x2 / double((2 * k) * (2 * k + 1)); s += t; }
    return s;
}
constexpr double ccos(double x) {
    double t = 1.0, s = 1.0; const double x2 = x * x;
    for (int k = 1; k < 13; ++k) { t *= -x2 / double((2 * k - 1) * (2 * k)); s += t; }
    return s;
}
// ---- constexpr double -> bf16 (RNE), arithmetic (no bit_cast) ----
constexpr unsigned short d2bf(double v) {
    unsigned short sgn = 0;
    if (v < 0) { sgn = 0x8000; v = -v; }
    if (v == 0) return sgn;
    int e = 0;
    while (v >= 2.0) { v *= 0.5; ++e; }
    while (v < 1.0)  { v *= 2.0; --e; }
    double m = (v - 1.0) * 128.0;            // 7-bit mantissa
    int mi = (int)m;
    const double frac = m - (double)mi;
    if (frac > 0.5 || (frac == 0.5 && (mi & 1))) ++mi;
    if (mi == 128) { mi = 0; ++e; }
    return (unsigned short)(sgn | ((unsigned)(e + 127) << 7) | (unsigned)mi);
}
constexpr double gval(int j) {               // g[j & 127]
    const int d = 2 * (j & 127) + 1;
    const double th = PI_D * (double)d / 256.0;
    const double s = ((d & 3) == 1) ? 1.0 : -1.0;
    return s * ccos(th) / (128.0 * csin(th));
}
// per-lane tap fragment table: [dd*64 + lane]*8 + e = g[(l15-8*l4+16*dd - e)&127]
struct GhTab { unsigned short v[8 * 64 * 8]; };
constexpr GhTab make_ghtab() {
    GhTab t{};
    for (int dd = 0; dd < 8; ++dd)
        for (int lane = 0; lane < 64; ++lane) {
            const int l15 = lane & 15, l4 = lane >> 4;
            const int base = l15 - 8 * l4 + 16 * dd;
            for (int e = 0; e < 8; ++e)
                t.v[(dd * 64 + lane) * 8 + e] = d2bf(gval(base - e));
        }
    return t;
}
__device__ constexpr GhTab GHTAB = make_ghtab();

__device__ __forceinline__ unsigned short f2bf(float x) {
    unsigned int b = __float_as_uint(x);
    return (unsigned short)((b + 0x7FFFu + ((b >> 16) & 1u)) >> 16);  // RNE
}

// byte-offset XOR swizzle within a 256B Et row (bits 4..6); same fn on W+R.
__device__ __forceinline__ int etswz(int row) {
    return (((row & 7) ^ (((row >> 3) & 3) << 1) ^ (((row >> 5) & 1) << 2)) << 4);
}

// ---- one (image, quarter) tile; optionally prefetches next tile's x rows ----
__device__ __forceinline__ void tile_phase(
    const unsigned short* __restrict__ ghtab,
    const float* __restrict__ xrow,       // this tile's x row base (lane's row)
    const float* __restrict__ nxrow,      // next tile's x row base, or nullptr
    float* __restrict__ oim,
    unsigned short* __restrict__ Et,      // 64*128 ushort buffer
    float4 (&xlo)[4], float4 (&xhi)[4],
    const int qb, const int lane, const int w,
    const int l15, const int l4, const int r)
{
    // cvt to xa (transient union, register-resident) + Et even-col writes
    bf16x8 xa[4];
    #pragma unroll
    for (int t = 0; t < 4; ++t) {
        union { bf16x8 v; unsigned short u[8]; } H;
        H.u[0] = f2bf(xlo[t].x); H.u[1] = f2bf(xlo[t].y);
        H.u[2] = f2bf(xlo[t].z); H.u[3] = f2bf(xlo[t].w);
        H.u[4] = f2bf(xhi[t].x); H.u[5] = f2bf(xhi[t].y);
        H.u[6] = f2bf(xhi[t].z); H.u[7] = f2bf(xhi[t].w);
        xa[t] = H.v;
        if (t == qb) {                             // covers this quarter's even c
            #pragma unroll
            for (int e = 0; e < 8; ++e) {
                const int row = 16 * l4 + 2 * e;
                Et[row * 128 + (((2 * r) ^ etswz(row)) >> 1)] = H.u[e];
            }
        }
    }

    // PREFETCH next tile's x rows into the SAME registers (x regs dead now).
    // These loads stay in flight across the lgkm-only barrier + phase B.
    if (nxrow) {
        #pragma unroll
        for (int t = 0; t < 4; ++t) {
            xlo[t] = *(const float4*)&nxrow[32 * t + 8 * l4];
            xhi[t] = *(const float4*)&nxrow[32 * t + 8 * l4 + 4];
        }
    }

    // Phase-A tap frags: 2qb folded into ADDRESS; register indices static.
    bf16x8 ghc[8];
    #pragma unroll
    for (int v = 0; v < 8; ++v) {
        const int dd = (v + 2 * qb) & 7;
        ghc[v] = *(const bf16x8*)&ghtab[(dd * 64 + lane) * 8];
    }

    // ---- phase A: odd-col tiles {2qb, 2qb+1}; even rows + Et odd cols ----
    float* __restrict__ orow = oim + (2 * r) * 256;
    #pragma unroll
    for (int j = 0; j < 2; ++j) {
        f32x4 acc = {0.f, 0.f, 0.f, 0.f};
        #pragma unroll
        for (int t = 0; t < 4; ++t)   // dd = (2qb+j-2t)&7 -> ghc[(j-2t)&7]
            acc = __builtin_amdgcn_mfma_f32_16x16x32_bf16(ghc[(j - 2 * t) & 7],
                                                          xa[t], acc, 0, 0, 0);
        const int i0g = 32 * qb + 16 * j + 4 * l4;
        float4 xc = *(const float4*)&xrow[i0g];    // L1/L2 hit, exact fp32
        float4 o0 = make_float4(xc.x, acc[0], xc.y, acc[1]);
        float4 o1 = make_float4(xc.z, acc[2], xc.w, acc[3]);
        *(float4*)&orow[2 * i0g]     = o0;
        *(float4*)&orow[2 * i0g + 4] = o1;
        #pragma unroll
        for (int q = 0; q < 4; ++q) {
            const int row = 2 * (16 * j + 4 * l4 + q) + 1;
            Et[row * 128 + (((2 * r) ^ etswz(row)) >> 1)] = f2bf(acc[q]);
        }
    }

    // LDS-only barrier (R16): order Et, do NOT drain in-flight global loads.
    asm volatile("s_waitcnt lgkmcnt(0)" ::: "memory");
    __builtin_amdgcn_s_barrier();
    __builtin_amdgcn_sched_barrier(0);

    // ---- phase B: odd rows for this quarter; 2-p-tile frag reuse ----
    {
        const int pa = w & 3;
        const int mh = w >> 2;
        bf16x8 gbd[4];
        #pragma unroll
        for (int d = 0; d < 4; ++d) {
            const int dd = (pa + 2 * d) & 7;
            gbd[d] = *(const bf16x8*)&ghtab[(dd * 64 + lane) * 8];
        }
        float* __restrict__ prowA = oim + (2 * (16 * pa + l15) + 1) * 256 + 64 * qb;
        float* __restrict__ prowB = oim + (2 * (16 * (pa + 4) + l15) + 1) * 256 + 64 * qb;
        #pragma unroll
        for (int mci = 0; mci < 2; ++mci) {
            const int mc = 2 * mh + mci;
            const int row = 16 * mc + l15;
            const char* erow = (const char*)Et + row * 256;
            const int sw = etswz(row);
            f32x4 aA = {0.f, 0.f, 0.f, 0.f};
            f32x4 aB = {0.f, 0.f, 0.f, 0.f};
            #pragma unroll
            for (int t = 0; t < 4; ++t) {
                bf16x8 ef = *(const bf16x8*)(erow + ((64 * t + 16 * l4) ^ sw));
                aA = __builtin_amdgcn_mfma_f32_16x16x32_bf16(ef, gbd[(-t) & 3], aA, 0, 0, 0);
                aB = __builtin_amdgcn_mfma_f32_16x16x32_bf16(ef, gbd[(2 - t) & 3], aB, 0, 0, 0);
            }
            float4 oA = make_float4(aA[0], aA[1], aA[2], aA[3]);
            float4 oB = make_float4(aB[0], aB[1], aB[2], aB[3]);
            *(float4*)&prowA[16 * mc + 4 * l4] = oA;
            *(float4*)&prowB[16 * mc + 4 * l4] = oB;
        }
    }
}

// ---- fused kernel: 2 images per block (same c-quarter), 512 thr (8 waves) ----
__global__ __launch_bounds__(512, 4)
void upsample_fused(const float* __restrict__ xin, float* __restrict__ out)
{
    __shared__ __align__(16) unsigned short Et0[64 * 128];  // 16KB
    __shared__ __align__(16) unsigned short Et1[64 * 128];  // 16KB

    const unsigned short* __restrict__ ghtab = GHTAB.v;

    const int tid  = threadIdx.x;
    const int lane = tid & 63;
    const int w    = tid >> 6;
    const int l15  = lane & 15;
    const int l4   = lane >> 4;

    const int bid = blockIdx.x;
    const int qb  = bid & 3;                        // column quarter
    const long long img0 = (long long)(bid >> 2) * 2;

    const float* __restrict__ xim0 = xin + img0 * (128LL * 128LL);
    const float* __restrict__ xim1 = xim0 + 128LL * 128LL;
    float* __restrict__ oim0 = out + img0 * (256LL * 256LL);
    float* __restrict__ oim1 = oim0 + 256LL * 256LL;

    const int r = 16 * w + l15;
    const float* __restrict__ xrow0 = xim0 + r * 128;
    const float* __restrict__ xrow1 = xim1 + r * 128;

    // tile0 x loads (all 8 dwordx4 in flight)
    float4 xlo[4], xhi[4];
    #pragma unroll
    for (int t = 0; t < 4; ++t) {
        xlo[t] = *(const float4*)&xrow0[32 * t + 8 * l4];
        xhi[t] = *(const float4*)&xrow0[32 * t + 8 * l4 + 4];
    }

    // tile 0: prefetches tile 1's x rows mid-flight
    tile_phase(ghtab, xrow0, xrow1, oim0, Et0, xlo, xhi, qb, lane, w, l15, l4, r);
    // tile 1: no prefetch
    tile_phase(ghtab, xrow1, nullptr, oim1, Et1, xlo, xhi, qb, lane, w, l15, l4, r);
}

extern "C" void kernel_launch(void* const* d_in, const int* in_sizes, int n_in,
                              void* d_out, int out_size, void* d_ws, size_t ws_size,
                              hipStream_t stream)
{
    (void)n_in; (void)out_size; (void)d_ws; (void)ws_size;
    const float* x = (const float*)d_in[0];
    float* out = (float*)d_out;
    int nimg = in_sizes[0] / (128 * 128);   // 1024 images (even)
    int nblk = (nimg >> 1) * 4;             // 2 images per block, 4 quarters

    hipLaunchKernelGGL(upsample_fused, dim3(nblk), dim3(512), 0, stream, x, out);
}

// Round 21
// 110.089 us; speedup vs baseline: 1.2058x; 1.2058x over previous
//
#include <hip/hip_runtime.h>

// UpsampleRFFT (zero-insert 2x + ideal half-band low-pass, circular), closed form:
//   g[j] = sign*cot(pi*(2j+1)/256)/128, sign=+ if j even
//   out[2r][2i]   = x[r][i] (exact fp32)      out[2r][2i+1] = T[r][i],  T = X*G
//   out[2p+1][c]  = sum_m g[(p-m)&127] * E[m][c],  E = even rows
// R21 = R19 (4 blocks/image c-quarters, 16KB Et, 91.0us best) + pre-barrier
// issue of phase-B tap loads: all waves hit the barrier together, then all
// stall ~200cyc on gbd global loads before the first phase-B MFMA. Issue gbd
// BEFORE the barrier (ghc/xa dead there -> no peak VGPR change) and use the
// R16 lgkm-only barrier so the loads stay in flight (plain __syncthreads
// drains vmcnt(0) and would serialize them).
//
// Kept lessons: rule #20 (static reg indices, runtime offsets in ADDRESSES);
// R10 no nt stores; R13 Et XOR swizzle + phase-B 2-p-tile frag reuse;
// R18 constexpr tap table; R20 lesson: NO cross-tile register prefetch.

typedef __bf16 bf16x8 __attribute__((ext_vector_type(8)));
typedef float  f32x4  __attribute__((ext_vector_type(4)));

#define PI_D 3.14159265358979323846

// ---- constexpr trig (Taylor, |x| <= pi, double: ~1e-11 rel) ----
constexpr double csin(double x) {
    double t = x, s = x; const double x2 = x * x;
    for (int k = 1; k < 13; ++k) { t *= -x2 / double((2 * k) * (2 * k + 1)); s += t; }
    return s;
}
constexpr double ccos(double x) {
    double t = 1.0, s = 1.0; const double x2 = x * x;
    for (int k = 1; k < 13; ++k) { t *= -x2 / double((2 * k - 1) * (2 * k)); s += t; }
    return s;
}
// ---- constexpr double -> bf16 (RNE), arithmetic (no bit_cast) ----
constexpr unsigned short d2bf(double v) {
    unsigned short sgn = 0;
    if (v < 0) { sgn = 0x8000; v = -v; }
    if (v == 0) return sgn;
    int e = 0;
    while (v >= 2.0) { v *= 0.5; ++e; }
    while (v < 1.0)  { v *= 2.0; --e; }
    double m = (v - 1.0) * 128.0;            // 7-bit mantissa
    int mi = (int)m;
    const double frac = m - (double)mi;
    if (frac > 0.5 || (frac == 0.5 && (mi & 1))) ++mi;
    if (mi == 128) { mi = 0; ++e; }
    return (unsigned short)(sgn | ((unsigned)(e + 127) << 7) | (unsigned)mi);
}
constexpr double gval(int j) {               // g[j & 127]
    const int d = 2 * (j & 127) + 1;
    const double th = PI_D * (double)d / 256.0;
    const double s = ((d & 3) == 1) ? 1.0 : -1.0;
    return s * ccos(th) / (128.0 * csin(th));
}
// per-lane tap fragment table: [dd*64 + lane]*8 + e = g[(l15-8*l4+16*dd - e)&127]
struct GhTab { unsigned short v[8 * 64 * 8]; };
constexpr GhTab make_ghtab() {
    GhTab t{};
    for (int dd = 0; dd < 8; ++dd)
        for (int lane = 0; lane < 64; ++lane) {
            const int l15 = lane & 15, l4 = lane >> 4;
            const int base = l15 - 8 * l4 + 16 * dd;
            for (int e = 0; e < 8; ++e)
                t.v[(dd * 64 + lane) * 8 + e] = d2bf(gval(base - e));
        }
    return t;
}
__device__ constexpr GhTab GHTAB = make_ghtab();

__device__ __forceinline__ unsigned short f2bf(float x) {
    unsigned int b = __float_as_uint(x);
    return (unsigned short)((b + 0x7FFFu + ((b >> 16) & 1u)) >> 16);  // RNE
}

// byte-offset XOR swizzle within a 256B Et row (bits 4..6); same fn on W+R.
__device__ __forceinline__ int etswz(int row) {
    return (((row & 7) ^ (((row >> 3) & 3) << 1) ^ (((row >> 5) & 1) << 2)) << 4);
}

// ---- fused kernel: 4 blocks/image (c-quarters), 512 threads (8 waves) ----
__global__ __launch_bounds__(512, 4)
void upsample_fused(const float* __restrict__ xin, float* __restrict__ out)
{
    __shared__ __align__(16) unsigned short Et[64 * 128]; // Et[c_loc][m], 16KB

    const unsigned short* __restrict__ ghtab = GHTAB.v;

    const int tid  = threadIdx.x;
    const int lane = tid & 63;
    const int w    = tid >> 6;        // 0..7: r-tile (A); (pa,mh) in phase B
    const int l15  = lane & 15;
    const int l4   = lane >> 4;

    const long long img = blockIdx.x >> 2;
    const int qb        = blockIdx.x & 3;          // column quarter
    const float* __restrict__ xim = xin + img * (128LL * 128LL);
    float*       __restrict__ oim = out + img * (256LL * 256LL);

    const int r = 16 * w + l15;
    const float* __restrict__ xrow = xim + r * 128;

    // issue full-row x loads first (K=128 needed for the W-conv)
    float4 xlo[4], xhi[4];
    #pragma unroll
    for (int t = 0; t < 4; ++t) {
        xlo[t] = *(const float4*)&xrow[32 * t + 8 * l4];
        xhi[t] = *(const float4*)&xrow[32 * t + 8 * l4 + 4];
    }

    // Phase-A tap frags: 2qb folded into the ADDRESS; register indices static.
    bf16x8 ghc[8];
    #pragma unroll
    for (int v = 0; v < 8; ++v) {
        const int dd = (v + 2 * qb) & 7;
        ghc[v] = *(const bf16x8*)&ghtab[(dd * 64 + lane) * 8];
    }

    // X fragments (transient union, register-resident) + even cols of E^T
    // for this quarter (only t == qb covers c_loc even rows).
    bf16x8 xa[4];
    #pragma unroll
    for (int t = 0; t < 4; ++t) {
        union { bf16x8 v; unsigned short u[8]; } H;
        H.u[0] = f2bf(xlo[t].x); H.u[1] = f2bf(xlo[t].y);
        H.u[2] = f2bf(xlo[t].z); H.u[3] = f2bf(xlo[t].w);
        H.u[4] = f2bf(xhi[t].x); H.u[5] = f2bf(xhi[t].y);
        H.u[6] = f2bf(xhi[t].z); H.u[7] = f2bf(xhi[t].w);
        xa[t] = H.v;
        if (t == qb) {                             // i = 32qb+8l4+e -> c_loc even
            #pragma unroll
            for (int e = 0; e < 8; ++e) {
                const int row = 16 * l4 + 2 * e;
                Et[row * 128 + (((2 * r) ^ etswz(row)) >> 1)] = H.u[e];
            }
        }
    }

    // ---- phase A: T = X*G (transposed); quarter = odd-col tiles {2qb, 2qb+1} ----
    float* __restrict__ orow = oim + (2 * r) * 256;
    #pragma unroll
    for (int j = 0; j < 2; ++j) {
        f32x4 acc = {0.f, 0.f, 0.f, 0.f};
        #pragma unroll
        for (int t = 0; t < 4; ++t)   // dd = (2qb+j-2t)&7 -> ghc[(j-2t)&7]
            acc = __builtin_amdgcn_mfma_f32_16x16x32_bf16(ghc[(j - 2 * t) & 7],
                                                          xa[t], acc, 0, 0, 0);
        const int i0g = 32 * qb + 16 * j + 4 * l4; // global odd-col index i
        float4 xc = *(const float4*)&xrow[i0g];    // L1 hit, exact fp32 copies
        float4 o0 = make_float4(xc.x, acc[0], xc.y, acc[1]);
        float4 o1 = make_float4(xc.z, acc[2], xc.w, acc[3]);
        *(float4*)&orow[2 * i0g]     = o0;
        *(float4*)&orow[2 * i0g + 4] = o1;
        #pragma unroll
        for (int q = 0; q < 4; ++q) {              // c_loc = 2*(16j+4l4+q)+1
            const int row = 2 * (16 * j + 4 * l4 + q) + 1;
            Et[row * 128 + (((2 * r) ^ etswz(row)) >> 1)] = f2bf(acc[q]);
        }
    }

    // Pre-barrier issue of phase-B tap frags (ghc/xa dead here -> no peak
    // pressure change). They stay in flight across the lgkm-only barrier.
    const int pa = w & 3;
    const int mh = w >> 2;
    bf16x8 gbd[4];
    #pragma unroll
    for (int d = 0; d < 4; ++d) {
        const int dd = (pa + 2 * d) & 7;
        gbd[d] = *(const bf16x8*)&ghtab[(dd * 64 + lane) * 8];
    }
    float* __restrict__ prowA = oim + (2 * (16 * pa + l15) + 1) * 256 + 64 * qb;
    float* __restrict__ prowB = oim + (2 * (16 * (pa + 4) + l15) + 1) * 256 + 64 * qb;

    // LDS-only barrier (R16): order Et writes; do NOT drain the in-flight
    // gbd loads (a plain __syncthreads would s_waitcnt vmcnt(0) here).
    asm volatile("s_waitcnt lgkmcnt(0)" ::: "memory");
    __builtin_amdgcn_s_barrier();
    __builtin_amdgcn_sched_barrier(0);   // rule #18: nothing hoists above

    // ---- phase B: odd[p][c] = sum_m g[(p-m)&127] * E[m][c], quarter cols ----
    //      wave -> p-tiles {pa, pa+4} (frag reuse), mc tiles {2mh, 2mh+1}
    {
        #pragma unroll
        for (int mci = 0; mci < 2; ++mci) {
            const int mc = 2 * mh + mci;           // local c-tile 0..3
            const int row = 16 * mc + l15;         // c_loc in [0,64)
            const char* erow = (const char*)Et + row * 256;
            const int sw = etswz(row);
            f32x4 aA = {0.f, 0.f, 0.f, 0.f};
            f32x4 aB = {0.f, 0.f, 0.f, 0.f};
            #pragma unroll
            for (int t = 0; t < 4; ++t) {
                bf16x8 ef = *(const bf16x8*)(erow + ((64 * t + 16 * l4) ^ sw));
                // pa: dd=(pa-2t)&7 -> d=(-t)&3 ; pa+4: dd=(pa+4-2t)&7 -> d=(2-t)&3
                aA = __builtin_amdgcn_mfma_f32_16x16x32_bf16(ef, gbd[(-t) & 3], aA, 0, 0, 0);
                aB = __builtin_amdgcn_mfma_f32_16x16x32_bf16(ef, gbd[(2 - t) & 3], aB, 0, 0, 0);
            }
            float4 oA = make_float4(aA[0], aA[1], aA[2], aA[3]);
            float4 oB = make_float4(aB[0], aB[1], aB[2], aB[3]);
            *(float4*)&prowA[16 * mc + 4 * l4] = oA;
            *(float4*)&prowB[16 * mc + 4 * l4] = oB;
        }
    }
}

extern "C" void kernel_launch(void* const* d_in, const int* in_sizes, int n_in,
                              void* d_out, int out_size, void* d_ws, size_t ws_size,
                              hipStream_t stream)
{
    (void)n_in; (void)out_size; (void)d_ws; (void)ws_size;
    const float* x = (const float*)d_in[0];
    float* out = (float*)d_out;
    int nimg = in_sizes[0] / (128 * 128);   // 1024 images

    hipLaunchKernelGGL(upsample_fused, dim3(nimg * 4), dim3(512), 0, stream, x, out);
}